// Round 1
// baseline (8330.225 us; speedup 1.0000x reference)
//
#include <hip/hip_runtime.h>

#define B_ 256
#define S_ 64
#define I_ 256
#define H_ 1024
#define NODE_ 4

typedef __attribute__((ext_vector_type(8))) short short8;
typedef __attribute__((ext_vector_type(4))) float f32x4;

// fp32 -> bf16 round-to-nearest-even on raw bits
__device__ __forceinline__ short f2bf(float f) {
    unsigned u = __float_as_uint(f);
    u += 0x7fffu + ((u >> 16) & 1u);
    return (short)(u >> 16);
}

#define LDS_LD 48   // shorts per LDS row (96B stride: 4-way-max bank aliasing on b128 reads)

__global__ void zero_kernel(float* __restrict__ p, int n) {
    int i = blockIdx.x * blockDim.x + threadIdx.x;
    if (i < n) p[i] = 0.f;
}

// Accumulate acc += A[64 x K] * W[64 x K]^T  (both staged fp32->bf16 via LDS).
// aptr/wptr are per-thread staging pointers (row srow, col offset scol applied).
__device__ __forceinline__ void mm_accum(const float* __restrict__ aptr,
                                         const float* __restrict__ wptr,
                                         int K,
                                         short* As, short* Ws,
                                         int srow, int scol,
                                         int wr, int wc, int r16, int kg,
                                         f32x4 acc[2][2])
{
    for (int k0 = 0; k0 < K; k0 += 32) {
        float4 av0 = *(const float4*)(aptr + k0);
        float4 av1 = *(const float4*)(aptr + k0 + 4);
        float4 wv0 = *(const float4*)(wptr + k0);
        float4 wv1 = *(const float4*)(wptr + k0 + 4);
        short8 as8 = { f2bf(av0.x), f2bf(av0.y), f2bf(av0.z), f2bf(av0.w),
                       f2bf(av1.x), f2bf(av1.y), f2bf(av1.z), f2bf(av1.w) };
        short8 ws8 = { f2bf(wv0.x), f2bf(wv0.y), f2bf(wv0.z), f2bf(wv0.w),
                       f2bf(wv1.x), f2bf(wv1.y), f2bf(wv1.z), f2bf(wv1.w) };
        *(short8*)&As[srow * LDS_LD + scol] = as8;
        *(short8*)&Ws[srow * LDS_LD + scol] = ws8;
        __syncthreads();
        const short8 a0 = *(const short8*)&As[(wr * 32 +  0 + r16) * LDS_LD + kg * 8];
        const short8 a1 = *(const short8*)&As[(wr * 32 + 16 + r16) * LDS_LD + kg * 8];
        const short8 b0 = *(const short8*)&Ws[(wc * 32 +  0 + r16) * LDS_LD + kg * 8];
        const short8 b1 = *(const short8*)&Ws[(wc * 32 + 16 + r16) * LDS_LD + kg * 8];
        acc[0][0] = __builtin_amdgcn_mfma_f32_16x16x32_bf16(a0, b0, acc[0][0], 0, 0, 0);
        acc[0][1] = __builtin_amdgcn_mfma_f32_16x16x32_bf16(a0, b1, acc[0][1], 0, 0, 0);
        acc[1][0] = __builtin_amdgcn_mfma_f32_16x16x32_bf16(a1, b0, acc[1][0], 0, 0, 0);
        acc[1][1] = __builtin_amdgcn_mfma_f32_16x16x32_bf16(a1, b1, acc[1][1], 0, 0, 0);
        __syncthreads();
    }
}

// MODE 0: Euler substep   out = hcur + dth * tanh(hcur @ W_ode^T + b_ode)
// MODE 1: RNN update      out = tanh(x[:,s,:] @ W_in^T + hcur @ W_h^T + b_in + b_h)
template <int MODE>
__global__ __launch_bounds__(256)
void step_kernel(const float* __restrict__ hcur,
                 float* __restrict__ out,
                 const float* __restrict__ x,
                 int s,
                 const float* __restrict__ t,
                 const float* __restrict__ W,      // W_ode (MODE 0) or W_h (MODE 1), [H,H]
                 const float* __restrict__ Win,    // [H,I] (MODE 1)
                 const float* __restrict__ bias0,  // b_ode (MODE 0) or b_in (MODE 1)
                 const float* __restrict__ bias1)  // b_h (MODE 1)
{
    __shared__ short As[64 * LDS_LD];
    __shared__ short Ws[64 * LDS_LD];

    const int tid = threadIdx.x;
    const int blk = blockIdx.x;
    const int bi = blk & 3;    // batch strip (64 rows)
    const int bj = blk >> 2;   // hout tile (64 cols)

    const int lane = tid & 63;
    const int wv = tid >> 6;
    const int wr = wv >> 1, wc = wv & 1;
    const int r16 = lane & 15, kg = lane >> 4;

    const int srow = tid >> 2;         // staging row 0..63
    const int scol = (tid & 3) * 8;    // staging col offset (floats)

    f32x4 acc[2][2] = {};

    // matmul over h (K = H)
    mm_accum(hcur + (bi * 64 + srow) * H_ + scol,
             W + (bj * 64 + srow) * H_ + scol,
             H_, As, Ws, srow, scol, wr, wc, r16, kg, acc);

    if (MODE == 1) {
        // matmul over x_s (K = I), accumulate into same acc
        mm_accum(x + ((bi * 64 + srow) * S_ + s) * I_ + scol,
                 Win + (bj * 64 + srow) * I_ + scol,
                 I_, As, Ws, srow, scol, wr, wc, r16, kg, acc);
    }

    float dth = 0.f;
    if (MODE == 0) dth = (t[s] - t[s - 1]) * 0.25f;

#pragma unroll
    for (int m = 0; m < 2; ++m)
#pragma unroll
        for (int n = 0; n < 2; ++n)
#pragma unroll
            for (int r = 0; r < 4; ++r) {
                int row = bi * 64 + wr * 32 + m * 16 + kg * 4 + r;
                int col = bj * 64 + wc * 32 + n * 16 + r16;
                float v = acc[m][n][r];
                if (MODE == 0) {
                    float hv = hcur[row * H_ + col];
                    out[row * H_ + col] = hv + dth * tanhf(v + bias0[col]);
                } else {
                    out[row * H_ + col] = tanhf(v + bias0[col] + bias1[col]);
                }
            }
}

extern "C" void kernel_launch(void* const* d_in, const int* in_sizes, int n_in,
                              void* d_out, int out_size, void* d_ws, size_t ws_size,
                              hipStream_t stream) {
    const float* x     = (const float*)d_in[0];
    const float* t     = (const float*)d_in[1];
    const float* W_in  = (const float*)d_in[2];
    const float* b_in  = (const float*)d_in[3];
    const float* W_h   = (const float*)d_in[4];
    const float* b_h   = (const float*)d_in[5];
    const float* W_ode = (const float*)d_in[6];
    const float* b_ode = (const float*)d_in[7];

    float* hA = (float*)d_ws;
    float* hB = hA + B_ * H_;

    zero_kernel<<<dim3((B_ * H_ + 255) / 256), dim3(256), 0, stream>>>(hA, B_ * H_);

    float* cur = hA;
    float* nxt = hB;
    dim3 grid(64), blk(256);

    for (int s = 0; s < S_; ++s) {
        if (s > 0) {
            for (int e = 0; e < NODE_; ++e) {
                step_kernel<0><<<grid, blk, 0, stream>>>(cur, nxt, nullptr, s, t,
                                                         W_ode, nullptr, b_ode, nullptr);
                float* tmp = cur; cur = nxt; nxt = tmp;
            }
        }
        float* dst = (s == S_ - 1) ? (float*)d_out : nxt;
        step_kernel<1><<<grid, blk, 0, stream>>>(cur, dst, x, s, t,
                                                 W_h, W_in, b_in, b_h);
        if (s < S_ - 1) { float* tmp = cur; cur = nxt; nxt = tmp; }
    }
}

// Round 3
// 5070.377 us; speedup vs baseline: 1.6429x; 1.6429x over previous
//
#include <hip/hip_runtime.h>

#define B_ 256
#define S_ 64
#define I_ 256
#define H_ 1024
#define NODE_ 4
#define NB 256   // persistent blocks: one 32x32 h-tile each (8 row strips x 32 col strips)

typedef __attribute__((ext_vector_type(8))) short short8;
typedef __attribute__((ext_vector_type(4))) float f32x4;

// fp32 -> bf16 round-to-nearest-even on raw bits
__device__ __forceinline__ short f2bf(float f) {
    unsigned u = __float_as_uint(f);
    u += 0x7fffu + ((u >> 16) & 1u);
    return (short)(u >> 16);
}

// Grid-wide barrier: monotonic counter, device-scope. All NB blocks resident
// (grid == 256 == #CUs; 64KB LDS caps 2 blocks/CU so capacity >= grid always).
__device__ __forceinline__ void gbar(unsigned* cnt, unsigned target) {
    __syncthreads();   // drains this block's vmem stores (compiler emits waitcnt vmcnt(0))
    if (threadIdx.x == 0) {
        __builtin_amdgcn_fence(__ATOMIC_RELEASE, "agent"); // wb XCD L2
        __hip_atomic_fetch_add(cnt, 1u, __ATOMIC_RELAXED, __HIP_MEMORY_SCOPE_AGENT);
        while (__hip_atomic_load(cnt, __ATOMIC_RELAXED, __HIP_MEMORY_SCOPE_AGENT) < target)
            __builtin_amdgcn_s_sleep(2);
        __builtin_amdgcn_fence(__ATOMIC_ACQUIRE, "agent"); // inv L1/L2
    }
    __syncthreads();
}

__global__ __launch_bounds__(256, 1)
void odernn_persist(const float* __restrict__ x, const float* __restrict__ t,
                    const float* __restrict__ W_in, const float* __restrict__ b_in,
                    const float* __restrict__ W_h, const float* __restrict__ b_h,
                    const float* __restrict__ W_ode, const float* __restrict__ b_ode,
                    float* __restrict__ out,
                    unsigned short* __restrict__ h0buf, unsigned short* __restrict__ h1buf,
                    unsigned* __restrict__ cnt)
{
    __shared__ short Wlds[32 * 1024];   // exactly 64 KB: bf16 W_ode col-slice, XOR-swizzled

    const int tid = threadIdx.x;
    const int blk = blockIdx.x;
    const int bi = blk >> 5;          // 0..7   row strip (32 batch rows)
    const int bj = blk & 31;          // 0..31  col strip (32 h columns)
    const int lane = tid & 63;
    const int wv = tid >> 6;
    const int wr = wv >> 1, wc = wv & 1;          // wave quadrant in the 32x32 tile
    const int r16 = lane & 15, kg = lane >> 4;

    // ---- prologue: stage W_ode[bj*32 .. +32][0..1024] as bf16 into LDS ----
    {
        const int c = tid >> 3;              // 0..31 slice row (= output col within strip)
        const int ks = (tid & 7) * 128;      // k segment
        const float* wsrc = W_ode + (size_t)(bj * 32 + c) * H_ + ks;
        for (int i = 0; i < 16; ++i) {
            float4 v0 = *(const float4*)(wsrc + i * 8);
            float4 v1 = *(const float4*)(wsrc + i * 8 + 4);
            short8 sv = { f2bf(v0.x), f2bf(v0.y), f2bf(v0.z), f2bf(v0.w),
                          f2bf(v1.x), f2bf(v1.y), f2bf(v1.z), f2bf(v1.w) };
            int idx = c * 1024 + ks + i * 8;
            *(short8*)&Wlds[idx ^ ((c & 7) << 3)] = sv;   // byte-XOR ((c&7)<<4)
        }
    }

    const int rowb = bi * 32 + wr * 16 + kg * 4;   // first of this thread's 4 output rows
    const int arow = bi * 32 + wr * 16 + r16;      // A-fragment row (batch)
    const int col  = bj * 32 + wc * 16 + r16;      // this thread's output column
    const int wb   = wc * 16 + r16;                // W-slice row for B-fragment

    const float bodec = b_ode[col];
    const float binc  = b_in[col] + b_h[col];

    f32x4 hreg = {0.f, 0.f, 0.f, 0.f};            // fp32 master h (thread-owned 4 elems)
#pragma unroll
    for (int r = 0; r < 4; ++r)                   // h0 = 0 published
        h0buf[(size_t)(rowb + r) * H_ + col] = 0;

    unsigned epoch = 1;
    gbar(cnt, NB * epoch); ++epoch;

    const unsigned short* hin = h0buf;
    unsigned short* hout = h1buf;

    for (int s = 0; s < S_; ++s) {
        if (s > 0) {
            const float dth = (t[s] - t[s - 1]) * 0.25f;
            for (int e = 0; e < NODE_; ++e) {
                // acc = h @ W_ode^T  (A from global bf16, B from LDS)
                f32x4 acc = {0.f, 0.f, 0.f, 0.f};
                const unsigned short* aB = hin + (size_t)arow * H_ + kg * 8;
#pragma unroll 8
                for (int k0 = 0; k0 < H_; k0 += 32) {
                    short8 a = *(const short8*)(aB + k0);
                    short8 b = *(const short8*)&Wlds[(wb * 1024 + k0 + kg * 8) ^ ((wb & 7) << 3)];
                    acc = __builtin_amdgcn_mfma_f32_16x16x32_bf16(a, b, acc, 0, 0, 0);
                }
#pragma unroll
                for (int r = 0; r < 4; ++r) {
                    hreg[r] += dth * tanhf(acc[r] + bodec);
                    hout[(size_t)(rowb + r) * H_ + col] = (unsigned short)f2bf(hreg[r]);
                }
                gbar(cnt, NB * epoch); ++epoch;
                const unsigned short* tmp = hin; hin = hout; hout = (unsigned short*)tmp;
            }
        }
        // ---- update: h = tanh(x_s @ W_in^T + h @ W_h^T + b_in + b_h) ----
        {
            f32x4 acc = {0.f, 0.f, 0.f, 0.f};
            const unsigned short* aB = hin + (size_t)arow * H_ + kg * 8;
            const float* whB = W_h + (size_t)col * H_ + kg * 8;
#pragma unroll 4
            for (int k0 = 0; k0 < H_; k0 += 32) {
                short8 a = *(const short8*)(aB + k0);
                float4 w0 = *(const float4*)(whB + k0);
                float4 w1 = *(const float4*)(whB + k0 + 4);
                short8 b = { f2bf(w0.x), f2bf(w0.y), f2bf(w0.z), f2bf(w0.w),
                             f2bf(w1.x), f2bf(w1.y), f2bf(w1.z), f2bf(w1.w) };
                acc = __builtin_amdgcn_mfma_f32_16x16x32_bf16(a, b, acc, 0, 0, 0);
            }
            const float* xB  = x + ((size_t)arow * S_ + s) * I_ + kg * 8;
            const float* wiB = W_in + (size_t)col * I_ + kg * 8;
#pragma unroll
            for (int k2 = 0; k2 < I_; k2 += 32) {
                float4 a0 = *(const float4*)(xB + k2);
                float4 a1 = *(const float4*)(xB + k2 + 4);
                float4 w0 = *(const float4*)(wiB + k2);
                float4 w1 = *(const float4*)(wiB + k2 + 4);
                short8 a = { f2bf(a0.x), f2bf(a0.y), f2bf(a0.z), f2bf(a0.w),
                             f2bf(a1.x), f2bf(a1.y), f2bf(a1.z), f2bf(a1.w) };
                short8 b = { f2bf(w0.x), f2bf(w0.y), f2bf(w0.z), f2bf(w0.w),
                             f2bf(w1.x), f2bf(w1.y), f2bf(w1.z), f2bf(w1.w) };
                acc = __builtin_amdgcn_mfma_f32_16x16x32_bf16(a, b, acc, 0, 0, 0);
            }
            const bool last = (s == S_ - 1);
#pragma unroll
            for (int r = 0; r < 4; ++r) {
                float v = tanhf(acc[r] + binc);
                hreg[r] = v;
                hout[(size_t)(rowb + r) * H_ + col] = (unsigned short)f2bf(v);
                if (last) out[(size_t)(rowb + r) * H_ + col] = v;
            }
            if (!last) {
                gbar(cnt, NB * epoch); ++epoch;
                const unsigned short* tmp = hin; hin = hout; hout = (unsigned short*)tmp;
            }
        }
    }
}

extern "C" void kernel_launch(void* const* d_in, const int* in_sizes, int n_in,
                              void* d_out, int out_size, void* d_ws, size_t ws_size,
                              hipStream_t stream) {
    const float* x     = (const float*)d_in[0];
    const float* t     = (const float*)d_in[1];
    const float* W_in  = (const float*)d_in[2];
    const float* b_in  = (const float*)d_in[3];
    const float* W_h   = (const float*)d_in[4];
    const float* b_h   = (const float*)d_in[5];
    const float* W_ode = (const float*)d_in[6];
    const float* b_ode = (const float*)d_in[7];

    unsigned short* h0 = (unsigned short*)d_ws;
    unsigned short* h1 = h0 + (size_t)B_ * H_;
    unsigned* cnt = (unsigned*)((char*)d_ws + (size_t)2 * B_ * H_ * sizeof(unsigned short));

    (void)hipMemsetAsync(cnt, 0, sizeof(unsigned), stream);

    odernn_persist<<<dim3(NB), dim3(256), 0, stream>>>(
        x, t, W_in, b_in, W_h, b_h, W_ode, b_ode,
        (float*)d_out, h0, h1, cnt);
}

// Round 4
// 3677.004 us; speedup vs baseline: 2.2655x; 1.3789x over previous
//
#include <hip/hip_runtime.h>

#define B_ 256
#define S_ 64
#define I_ 256
#define H_ 1024
#define NODE_ 4
#define NB 256
#define NG 8     // row groups (32 batch rows each) -- data-decoupled, own barrier
#define GSZ 32   // blocks per group (one 32-col strip each)

typedef __attribute__((ext_vector_type(8))) short short8;
typedef __attribute__((ext_vector_type(4))) float f32x4;

// fp32 -> bf16 round-to-nearest-even on raw bits
__device__ __forceinline__ short f2bf(float f) {
    unsigned u = __float_as_uint(f);
    u += 0x7fffu + ((u >> 16) & 1u);
    return (short)(u >> 16);
}
__device__ __forceinline__ unsigned pack2(float a, float b) {
    return (unsigned)(unsigned short)f2bf(a) | ((unsigned)(unsigned short)f2bf(b) << 16);
}

// 16B of bf16 h, coherent at device scope (bypasses L1/L2 -> LLC). RELAXED:
// ordering vs the barrier is by control dependence + producer-side release.
__device__ __forceinline__ short8 ld_h16(const unsigned long long* p) {
    union { unsigned long long u[2]; short8 s; } v;
    v.u[0] = __hip_atomic_load(p,     __ATOMIC_RELAXED, __HIP_MEMORY_SCOPE_AGENT);
    v.u[1] = __hip_atomic_load(p + 1, __ATOMIC_RELAXED, __HIP_MEMORY_SCOPE_AGENT);
    return v.s;
}

// Group barrier: monotonic counter. RELEASE on arrive orders this block's
// (write-through) h stores before the count at the LLC; consumers' h loads
// bypass L1/L2 so no acquire fence (no buffer_inv -> L2 weights stay warm).
__device__ __forceinline__ void gbar(unsigned* cnt, unsigned target) {
    __syncthreads();
    if (threadIdx.x == 0) {
        __hip_atomic_fetch_add(cnt, 1u, __ATOMIC_RELEASE, __HIP_MEMORY_SCOPE_AGENT);
        while (__hip_atomic_load(cnt, __ATOMIC_RELAXED, __HIP_MEMORY_SCOPE_AGENT) < target)
            __builtin_amdgcn_s_sleep(1);
    }
    __syncthreads();
}

__global__ __launch_bounds__(256, 1)
void odernn_persist(const float* __restrict__ x, const float* __restrict__ t,
                    const float* __restrict__ W_in, const float* __restrict__ b_in,
                    const float* __restrict__ W_h, const float* __restrict__ b_h,
                    const float* __restrict__ W_ode, const float* __restrict__ b_ode,
                    float* __restrict__ out,
                    unsigned short* __restrict__ h0buf, unsigned short* __restrict__ h1buf,
                    unsigned short* __restrict__ Whbf, unsigned short* __restrict__ Winbf,
                    unsigned* __restrict__ cnts)
{
    __shared__ short Wlds[32 * 1024];   // 64 KB: bf16 W_ode col-slice, XOR-swizzled

    const int tid = threadIdx.x;
    const int blk = blockIdx.x;
    const int bi = blk & 7;           // row group (32 batch rows); blk%8 -> one XCD
    const int bj = blk >> 3;          // 0..31 col strip
    const int lane = tid & 63;
    const int wv = tid >> 6;
    const int wr = wv >> 1, wc = wv & 1;
    const int r16 = lane & 15, kg = lane >> 4;

    // ---- prologue A: convert W_h, W_in to bf16 in ws (disjoint chunks) ----
    {
        const int g = blk * 256 + tid;              // 0..65535
        const float* src = W_h + (size_t)g * 16;    // 16 floats each
        unsigned* dst = (unsigned*)Whbf + (size_t)g * 8;
#pragma unroll
        for (int i = 0; i < 4; ++i) {
            float4 v = *(const float4*)(src + i * 4);
            __hip_atomic_store(dst + i * 2,     pack2(v.x, v.y), __ATOMIC_RELAXED, __HIP_MEMORY_SCOPE_AGENT);
            __hip_atomic_store(dst + i * 2 + 1, pack2(v.z, v.w), __ATOMIC_RELAXED, __HIP_MEMORY_SCOPE_AGENT);
        }
        float4 v = *(const float4*)(W_in + (size_t)g * 4);
        unsigned* d2 = (unsigned*)Winbf + (size_t)g * 2;
        __hip_atomic_store(d2,     pack2(v.x, v.y), __ATOMIC_RELAXED, __HIP_MEMORY_SCOPE_AGENT);
        __hip_atomic_store(d2 + 1, pack2(v.z, v.w), __ATOMIC_RELAXED, __HIP_MEMORY_SCOPE_AGENT);
    }

    // ---- prologue B: stage W_ode[bj*32 .. +32][:] as bf16 into LDS ----
    {
        const int c = tid >> 3;
        const int ks = (tid & 7) * 128;
        const float* wsrc = W_ode + (size_t)(bj * 32 + c) * H_ + ks;
        for (int i = 0; i < 16; ++i) {
            float4 v0 = *(const float4*)(wsrc + i * 8);
            float4 v1 = *(const float4*)(wsrc + i * 8 + 4);
            short8 sv = { f2bf(v0.x), f2bf(v0.y), f2bf(v0.z), f2bf(v0.w),
                          f2bf(v1.x), f2bf(v1.y), f2bf(v1.z), f2bf(v1.w) };
            int idx = c * 1024 + ks + i * 8;
            *(short8*)&Wlds[idx ^ ((c & 7) << 3)] = sv;
        }
    }

    const int rowb = bi * 32 + wr * 16 + kg * 4;   // first of 4 output rows
    const int arow = bi * 32 + wr * 16 + r16;      // A-fragment row (batch)
    const int col  = bj * 32 + wc * 16 + r16;      // output column
    const int wb   = wc * 16 + r16;                // W-slice row for B-fragment

    const float bodec = b_ode[col];
    const float binc  = b_in[col] + b_h[col];

    f32x4 hreg = {0.f, 0.f, 0.f, 0.f};
#pragma unroll
    for (int r = 0; r < 4; ++r)   // publish h0 = 0 (device-coherent)
        __hip_atomic_store(&h0buf[(size_t)(rowb + r) * H_ + col], (unsigned short)0,
                           __ATOMIC_RELAXED, __HIP_MEMORY_SCOPE_AGENT);

    // one GLOBAL barrier: weights converted + h0 visible everywhere
    gbar(cnts + NG * 64, NB);

    unsigned* gc = cnts + bi * 64;   // this group's counter (256B-spaced lines)
    unsigned tar = GSZ;

    const unsigned short* hin = h0buf;
    unsigned short* hout = h1buf;

    for (int s = 0; s < S_; ++s) {
        if (s > 0) {
            const float dth = (t[s] - t[s - 1]) * 0.25f;
            for (int e = 0; e < NODE_; ++e) {
                f32x4 acc = {0.f, 0.f, 0.f, 0.f};
                const unsigned long long* aU =
                    (const unsigned long long*)hin + (((size_t)arow * H_ + kg * 8) >> 2);
#pragma unroll 8
                for (int k0 = 0; k0 < H_; k0 += 32) {
                    short8 a = ld_h16(aU + (k0 >> 2));
                    short8 b = *(const short8*)&Wlds[(wb * 1024 + k0 + kg * 8) ^ ((wb & 7) << 3)];
                    acc = __builtin_amdgcn_mfma_f32_16x16x32_bf16(a, b, acc, 0, 0, 0);
                }
#pragma unroll
                for (int r = 0; r < 4; ++r) {
                    hreg[r] += dth * tanhf(acc[r] + bodec);
                    __hip_atomic_store(&hout[(size_t)(rowb + r) * H_ + col],
                                       (unsigned short)f2bf(hreg[r]),
                                       __ATOMIC_RELAXED, __HIP_MEMORY_SCOPE_AGENT);
                }
                gbar(gc, tar); tar += GSZ;
                const unsigned short* tmp = hin; hin = hout; hout = (unsigned short*)tmp;
            }
        }
        // ---- update: h = tanh(x_s @ W_in^T + h @ W_h^T + b_in + b_h) ----
        {
            f32x4 acc = {0.f, 0.f, 0.f, 0.f};
            const unsigned long long* aU =
                (const unsigned long long*)hin + (((size_t)arow * H_ + kg * 8) >> 2);
            const unsigned short* whB = Whbf + (size_t)col * H_ + kg * 8;
#pragma unroll 8
            for (int k0 = 0; k0 < H_; k0 += 32) {
                short8 a = ld_h16(aU + (k0 >> 2));
                short8 b = *(const short8*)(whB + k0);
                acc = __builtin_amdgcn_mfma_f32_16x16x32_bf16(a, b, acc, 0, 0, 0);
            }
            const float* xB = x + ((size_t)arow * S_ + s) * I_ + kg * 8;
            const unsigned short* wiB = Winbf + (size_t)col * I_ + kg * 8;
#pragma unroll
            for (int k2 = 0; k2 < I_; k2 += 32) {
                float4 a0 = *(const float4*)(xB + k2);
                float4 a1 = *(const float4*)(xB + k2 + 4);
                short8 a = { f2bf(a0.x), f2bf(a0.y), f2bf(a0.z), f2bf(a0.w),
                             f2bf(a1.x), f2bf(a1.y), f2bf(a1.z), f2bf(a1.w) };
                short8 b = *(const short8*)(wiB + k2);
                acc = __builtin_amdgcn_mfma_f32_16x16x32_bf16(a, b, acc, 0, 0, 0);
            }
            const bool last = (s == S_ - 1);
#pragma unroll
            for (int r = 0; r < 4; ++r) {
                float v = tanhf(acc[r] + binc);
                hreg[r] = v;
                if (last) {
                    out[(size_t)(rowb + r) * H_ + col] = v;
                } else {
                    __hip_atomic_store(&hout[(size_t)(rowb + r) * H_ + col],
                                       (unsigned short)f2bf(v),
                                       __ATOMIC_RELAXED, __HIP_MEMORY_SCOPE_AGENT);
                }
            }
            if (!last) {
                gbar(gc, tar); tar += GSZ;
                const unsigned short* tmp = hin; hin = hout; hout = (unsigned short*)tmp;
            }
        }
    }
}

extern "C" void kernel_launch(void* const* d_in, const int* in_sizes, int n_in,
                              void* d_out, int out_size, void* d_ws, size_t ws_size,
                              hipStream_t stream) {
    const float* x     = (const float*)d_in[0];
    const float* t     = (const float*)d_in[1];
    const float* W_in  = (const float*)d_in[2];
    const float* b_in  = (const float*)d_in[3];
    const float* W_h   = (const float*)d_in[4];
    const float* b_h   = (const float*)d_in[5];
    const float* W_ode = (const float*)d_in[6];
    const float* b_ode = (const float*)d_in[7];

    unsigned short* h0    = (unsigned short*)d_ws;
    unsigned short* h1    = h0 + (size_t)B_ * H_;
    unsigned short* Whbf  = h1 + (size_t)B_ * H_;
    unsigned short* Winbf = Whbf + (size_t)H_ * H_;
    unsigned* cnts = (unsigned*)(Winbf + (size_t)H_ * I_);   // NG*64 + 1 uints

    (void)hipMemsetAsync(cnts, 0, (NG * 64 + 1) * sizeof(unsigned), stream);

    odernn_persist<<<dim3(NB), dim3(256), 0, stream>>>(
        x, t, W_in, b_in, W_h, b_h, W_ode, b_ode,
        (float*)d_out, h0, h1, Whbf, Winbf, cnts);
}

// Round 5
// 3064.981 us; speedup vs baseline: 2.7179x; 1.1997x over previous
//
#include <hip/hip_runtime.h>

#define B_ 256
#define S_ 64
#define I_ 256
#define H_ 1024
#define NODE_ 4
#define NB 256
#define NG 8     // row groups (32 batch rows each) -- data-decoupled, own barrier
#define GSZ 32   // blocks per group (one 32-col strip each)

typedef __attribute__((ext_vector_type(8))) short short8;
typedef __attribute__((ext_vector_type(4))) float f32x4;

// fp32 -> bf16 round-to-nearest-even on raw bits
__device__ __forceinline__ short f2bf(float f) {
    unsigned u = __float_as_uint(f);
    u += 0x7fffu + ((u >> 16) & 1u);
    return (short)(u >> 16);
}
__device__ __forceinline__ unsigned pack2(float a, float b) {
    return (unsigned)(unsigned short)f2bf(a) | ((unsigned)(unsigned short)f2bf(b) << 16);
}

// fast tanh: |err| ~1e-7 rel, negligible vs bf16 h quantization
__device__ __forceinline__ float ftanh(float x) {
    float e = __expf(2.0f * fabsf(x));
    float r = __builtin_fmaf(-2.0f, __builtin_amdgcn_rcpf(e + 1.0f), 1.0f);
    return copysignf(r, x);
}

// Group barrier: monotonic counter at LLC. RELAXED arrive: h stores are
// write-through (sc0 sc1) and __syncthreads drains vmcnt before s_barrier,
// so they are complete at the coherence point before the add issues.
// No release -> no buffer_wbl2; no acquire -> L2 weights stay warm.
__device__ __forceinline__ void gbar(unsigned* cnt, unsigned target) {
    __syncthreads();
    if (threadIdx.x == 0) {
        __hip_atomic_fetch_add(cnt, 1u, __ATOMIC_RELAXED, __HIP_MEMORY_SCOPE_AGENT);
        while (__hip_atomic_load(cnt, __ATOMIC_RELAXED, __HIP_MEMORY_SCOPE_AGENT) < target)
            __builtin_amdgcn_s_sleep(1);
    }
    __syncthreads();
}

// chunk = 8 k-steps (k0 = c*256 .. +256 in shorts) = 16 u64 per lane
#define LOADCHUNK(buf, c)                                                            \
    _Pragma("unroll") for (int i_ = 0; i_ < 8; ++i_) {                               \
        buf[2 * i_]     = __hip_atomic_load(aU + ((c) * 8 + i_) * 8,                 \
                              __ATOMIC_RELAXED, __HIP_MEMORY_SCOPE_AGENT);           \
        buf[2 * i_ + 1] = __hip_atomic_load(aU + ((c) * 8 + i_) * 8 + 1,             \
                              __ATOMIC_RELAXED, __HIP_MEMORY_SCOPE_AGENT);           \
    }

#define MFMACHUNK_LDS(buf, c)                                                        \
    _Pragma("unroll") for (int i_ = 0; i_ < 8; ++i_) {                               \
        union { unsigned long long u[2]; short8 s; } uv_;                            \
        uv_.u[0] = buf[2 * i_]; uv_.u[1] = buf[2 * i_ + 1];                          \
        short8 b_ = *(const short8*)&Wlds[(wb * 1024 + ((c) * 8 + i_) * 32 + kg * 8) \
                                          ^ ((wb & 7) << 3)];                        \
        acc = __builtin_amdgcn_mfma_f32_16x16x32_bf16(uv_.s, b_, acc, 0, 0, 0);      \
    }

#define MFMACHUNK_GLB(buf, c)                                                        \
    _Pragma("unroll") for (int i_ = 0; i_ < 8; ++i_) {                               \
        union { unsigned long long u[2]; short8 s; } uv_;                            \
        uv_.u[0] = buf[2 * i_]; uv_.u[1] = buf[2 * i_ + 1];                          \
        short8 b_ = *(const short8*)(whB + ((c) * 8 + i_) * 32);                     \
        acc = __builtin_amdgcn_mfma_f32_16x16x32_bf16(uv_.s, b_, acc, 0, 0, 0);      \
    }

__global__ __launch_bounds__(256, 1)
void odernn_persist(const float* __restrict__ x, const float* __restrict__ t,
                    const float* __restrict__ W_in, const float* __restrict__ b_in,
                    const float* __restrict__ W_h, const float* __restrict__ b_h,
                    const float* __restrict__ W_ode, const float* __restrict__ b_ode,
                    float* __restrict__ out,
                    unsigned short* __restrict__ h0buf, unsigned short* __restrict__ h1buf,
                    unsigned short* __restrict__ Whbf, unsigned short* __restrict__ Winbf,
                    unsigned* __restrict__ cnts)
{
    __shared__ short Wlds[32 * 1024];   // 64 KB: bf16 W_ode col-slice, XOR-swizzled

    const int tid = threadIdx.x;
    const int blk = blockIdx.x;
    const int bi = blk & 7;           // row group (32 batch rows); blk%8 -> one XCD
    const int bj = blk >> 3;          // 0..31 col strip
    const int lane = tid & 63;
    const int wv = tid >> 6;
    const int wr = wv >> 1, wc = wv & 1;
    const int r16 = lane & 15, kg = lane >> 4;

    // ---- prologue A: convert W_h, W_in to bf16 in ws (disjoint chunks) ----
    {
        const int g = blk * 256 + tid;              // 0..65535
        const float* src = W_h + (size_t)g * 16;    // 16 floats each
        unsigned* dst = (unsigned*)Whbf + (size_t)g * 8;
#pragma unroll
        for (int i = 0; i < 4; ++i) {
            float4 v = *(const float4*)(src + i * 4);
            __hip_atomic_store(dst + i * 2,     pack2(v.x, v.y), __ATOMIC_RELAXED, __HIP_MEMORY_SCOPE_AGENT);
            __hip_atomic_store(dst + i * 2 + 1, pack2(v.z, v.w), __ATOMIC_RELAXED, __HIP_MEMORY_SCOPE_AGENT);
        }
        float4 v = *(const float4*)(W_in + (size_t)g * 4);
        unsigned* d2 = (unsigned*)Winbf + (size_t)g * 2;
        __hip_atomic_store(d2,     pack2(v.x, v.y), __ATOMIC_RELAXED, __HIP_MEMORY_SCOPE_AGENT);
        __hip_atomic_store(d2 + 1, pack2(v.z, v.w), __ATOMIC_RELAXED, __HIP_MEMORY_SCOPE_AGENT);
    }

    // ---- prologue B: stage W_ode[bj*32 .. +32][:] as bf16 into LDS ----
    {
        const int c = tid >> 3;
        const int ks = (tid & 7) * 128;
        const float* wsrc = W_ode + (size_t)(bj * 32 + c) * H_ + ks;
        for (int i = 0; i < 16; ++i) {
            float4 v0 = *(const float4*)(wsrc + i * 8);
            float4 v1 = *(const float4*)(wsrc + i * 8 + 4);
            short8 sv = { f2bf(v0.x), f2bf(v0.y), f2bf(v0.z), f2bf(v0.w),
                          f2bf(v1.x), f2bf(v1.y), f2bf(v1.z), f2bf(v1.w) };
            int idx = c * 1024 + ks + i * 8;
            *(short8*)&Wlds[idx ^ ((c & 7) << 3)] = sv;
        }
    }

    const int rowb = bi * 32 + wr * 16 + kg * 4;   // first of 4 output rows
    const int arow = bi * 32 + wr * 16 + r16;      // A-fragment row (batch)
    const int col  = bj * 32 + wc * 16 + r16;      // output column
    const int wb   = wc * 16 + r16;                // W-slice row for B-fragment

    const float bodec = b_ode[col];
    const float binc  = b_in[col] + b_h[col];

    f32x4 hreg = {0.f, 0.f, 0.f, 0.f};
#pragma unroll
    for (int r = 0; r < 4; ++r)   // publish h0 = 0 (device-coherent)
        __hip_atomic_store(&h0buf[(size_t)(rowb + r) * H_ + col], (unsigned short)0,
                           __ATOMIC_RELAXED, __HIP_MEMORY_SCOPE_AGENT);

    // one GLOBAL barrier: weights converted + h0 visible everywhere
    gbar(cnts + NG * 64, NB);

    unsigned* gc = cnts + bi * 64;   // this group's counter (256B-spaced lines)
    unsigned tar = GSZ;

    const unsigned short* hin = h0buf;
    unsigned short* hout = h1buf;

    for (int s = 0; s < S_; ++s) {
        if (s > 0) {
            const float dth = (t[s] - t[s - 1]) * 0.25f;
            for (int e = 0; e < NODE_; ++e) {
                f32x4 acc = {0.f, 0.f, 0.f, 0.f};
                const unsigned long long* aU =
                    (const unsigned long long*)hin + (((size_t)arow * H_ + kg * 8) >> 2);
                unsigned long long hA_[16], hB_[16];
                LOADCHUNK(hA_, 0);
                LOADCHUNK(hB_, 1);
                MFMACHUNK_LDS(hA_, 0);
                LOADCHUNK(hA_, 2);
                MFMACHUNK_LDS(hB_, 1);
                LOADCHUNK(hB_, 3);
                MFMACHUNK_LDS(hA_, 2);
                MFMACHUNK_LDS(hB_, 3);
#pragma unroll
                for (int r = 0; r < 4; ++r) {
                    hreg[r] += dth * ftanh(acc[r] + bodec);
                    __hip_atomic_store(&hout[(size_t)(rowb + r) * H_ + col],
                                       (unsigned short)f2bf(hreg[r]),
                                       __ATOMIC_RELAXED, __HIP_MEMORY_SCOPE_AGENT);
                }
                gbar(gc, tar); tar += GSZ;
                const unsigned short* tmp = hin; hin = hout; hout = (unsigned short*)tmp;
            }
        }
        // ---- update: h = tanh(x_s @ W_in^T + h @ W_h^T + b_in + b_h) ----
        {
            f32x4 acc = {0.f, 0.f, 0.f, 0.f};
            const unsigned long long* aU =
                (const unsigned long long*)hin + (((size_t)arow * H_ + kg * 8) >> 2);
            const unsigned short* whB = Whbf + (size_t)col * H_ + kg * 8;
            unsigned long long hA_[16], hB_[16];
            LOADCHUNK(hA_, 0);
            LOADCHUNK(hB_, 1);
            MFMACHUNK_GLB(hA_, 0);
            LOADCHUNK(hA_, 2);
            MFMACHUNK_GLB(hB_, 1);
            LOADCHUNK(hB_, 3);
            MFMACHUNK_GLB(hA_, 2);
            MFMACHUNK_GLB(hB_, 3);
            const float* xB = x + ((size_t)arow * S_ + s) * I_ + kg * 8;
            const unsigned short* wiB = Winbf + (size_t)col * I_ + kg * 8;
#pragma unroll
            for (int k2 = 0; k2 < I_; k2 += 32) {
                float4 a0 = *(const float4*)(xB + k2);
                float4 a1 = *(const float4*)(xB + k2 + 4);
                short8 a = { f2bf(a0.x), f2bf(a0.y), f2bf(a0.z), f2bf(a0.w),
                             f2bf(a1.x), f2bf(a1.y), f2bf(a1.z), f2bf(a1.w) };
                short8 b = *(const short8*)(wiB + k2);
                acc = __builtin_amdgcn_mfma_f32_16x16x32_bf16(a, b, acc, 0, 0, 0);
            }
            const bool last = (s == S_ - 1);
#pragma unroll
            for (int r = 0; r < 4; ++r) {
                float v = ftanh(acc[r] + binc);
                hreg[r] = v;
                if (last) {
                    out[(size_t)(rowb + r) * H_ + col] = v;
                } else {
                    __hip_atomic_store(&hout[(size_t)(rowb + r) * H_ + col],
                                       (unsigned short)f2bf(v),
                                       __ATOMIC_RELAXED, __HIP_MEMORY_SCOPE_AGENT);
                }
            }
            if (!last) {
                gbar(gc, tar); tar += GSZ;
                const unsigned short* tmp = hin; hin = hout; hout = (unsigned short*)tmp;
            }
        }
    }
}

extern "C" void kernel_launch(void* const* d_in, const int* in_sizes, int n_in,
                              void* d_out, int out_size, void* d_ws, size_t ws_size,
                              hipStream_t stream) {
    const float* x     = (const float*)d_in[0];
    const float* t     = (const float*)d_in[1];
    const float* W_in  = (const float*)d_in[2];
    const float* b_in  = (const float*)d_in[3];
    const float* W_h   = (const float*)d_in[4];
    const float* b_h   = (const float*)d_in[5];
    const float* W_ode = (const float*)d_in[6];
    const float* b_ode = (const float*)d_in[7];

    unsigned short* h0    = (unsigned short*)d_ws;
    unsigned short* h1    = h0 + (size_t)B_ * H_;
    unsigned short* Whbf  = h1 + (size_t)B_ * H_;
    unsigned short* Winbf = Whbf + (size_t)H_ * H_;
    unsigned* cnts = (unsigned*)(Winbf + (size_t)H_ * I_);   // NG*64 + 1 uints

    (void)hipMemsetAsync(cnts, 0, (NG * 64 + 1) * sizeof(unsigned), stream);

    odernn_persist<<<dim3(NB), dim3(256), 0, stream>>>(
        x, t, W_in, b_in, W_h, b_h, W_ode, b_ode,
        (float*)d_out, h0, h1, Whbf, Winbf, cnts);
}

// Round 6
// 1345.124 us; speedup vs baseline: 6.1929x; 2.2786x over previous
//
#include <hip/hip_runtime.h>

#define B_ 256
#define S_ 64
#define I_ 256
#define H_ 1024
#define NODE_ 4
#define NB 256
#define NG 8     // row groups (32 batch rows each) -- data-decoupled, own barrier
#define GSZ 32   // blocks per group (one 32-col strip each)

typedef __attribute__((ext_vector_type(8))) short short8;
typedef __attribute__((ext_vector_type(4))) float f32x4;

// fp32 -> bf16 round-to-nearest-even on raw bits
__device__ __forceinline__ short f2bf(float f) {
    unsigned u = __float_as_uint(f);
    u += 0x7fffu + ((u >> 16) & 1u);
    return (short)(u >> 16);
}
__device__ __forceinline__ unsigned pack2(float a, float b) {
    return (unsigned)(unsigned short)f2bf(a) | ((unsigned)(unsigned short)f2bf(b) << 16);
}

// fast tanh: |err| ~1e-7 rel, negligible vs bf16 h quantization
__device__ __forceinline__ float ftanh(float x) {
    float e = __expf(2.0f * fabsf(x));
    float r = __builtin_fmaf(-2.0f, __builtin_amdgcn_rcpf(e + 1.0f), 1.0f);
    return copysignf(r, x);
}

// Group barrier: monotonic counter at LLC. RELAXED arrive: h stores are
// write-through (sc0 sc1) and __syncthreads drains vmcnt before s_barrier,
// so they are complete at the coherence point before the add issues.
__device__ __forceinline__ void gbar(unsigned* cnt, unsigned target) {
    __syncthreads();
    if (threadIdx.x == 0) {
        __hip_atomic_fetch_add(cnt, 1u, __ATOMIC_RELAXED, __HIP_MEMORY_SCOPE_AGENT);
        while (__hip_atomic_load(cnt, __ATOMIC_RELAXED, __HIP_MEMORY_SCOPE_AGENT) < target)
            __builtin_amdgcn_s_sleep(1);
    }
    __syncthreads();
}

__global__ __launch_bounds__(256, 1)
void odernn_persist(const float* __restrict__ x, const float* __restrict__ t,
                    const float* __restrict__ W_in, const float* __restrict__ b_in,
                    const float* __restrict__ W_h, const float* __restrict__ b_h,
                    const float* __restrict__ W_ode, const float* __restrict__ b_ode,
                    float* __restrict__ out,
                    unsigned short* __restrict__ h0buf, unsigned short* __restrict__ h1buf,
                    unsigned short* __restrict__ Whbf, unsigned short* __restrict__ Winbf,
                    unsigned* __restrict__ cnts)
{
    __shared__ short Wlds[32 * 1024];   // 64 KB: bf16 W_ode col-slice, XOR-swizzled
    __shared__ short Hlds[32 * 1024];   // 64 KB: staged h strip (32 rows x 1024), swizzled

    const int tid = threadIdx.x;
    const int blk = blockIdx.x;
    const int bi = blk & 7;           // row group (32 batch rows); blk%8 -> one XCD
    const int bj = blk >> 3;          // 0..31 col strip
    const int lane = tid & 63;
    const int wv = tid >> 6;
    const int wr = wv >> 1, wc = wv & 1;
    const int r16 = lane & 15, kg = lane >> 4;

    // ---- prologue A: convert W_h, W_in to bf16 in ws (disjoint chunks) ----
    {
        const int g = blk * 256 + tid;              // 0..65535
        const float* src = W_h + (size_t)g * 16;    // 16 floats each
        unsigned* dst = (unsigned*)Whbf + (size_t)g * 8;
#pragma unroll
        for (int i = 0; i < 4; ++i) {
            float4 v = *(const float4*)(src + i * 4);
            __hip_atomic_store(dst + i * 2,     pack2(v.x, v.y), __ATOMIC_RELAXED, __HIP_MEMORY_SCOPE_AGENT);
            __hip_atomic_store(dst + i * 2 + 1, pack2(v.z, v.w), __ATOMIC_RELAXED, __HIP_MEMORY_SCOPE_AGENT);
        }
        float4 v = *(const float4*)(W_in + (size_t)g * 4);
        unsigned* d2 = (unsigned*)Winbf + (size_t)g * 2;
        __hip_atomic_store(d2,     pack2(v.x, v.y), __ATOMIC_RELAXED, __HIP_MEMORY_SCOPE_AGENT);
        __hip_atomic_store(d2 + 1, pack2(v.z, v.w), __ATOMIC_RELAXED, __HIP_MEMORY_SCOPE_AGENT);
    }

    // ---- prologue B: stage W_ode[bj*32 .. +32][:] as bf16 into LDS ----
    {
        const int c = tid >> 3;
        const int ks = (tid & 7) * 128;
        const float* wsrc = W_ode + (size_t)(bj * 32 + c) * H_ + ks;
        for (int i = 0; i < 16; ++i) {
            float4 v0 = *(const float4*)(wsrc + i * 8);
            float4 v1 = *(const float4*)(wsrc + i * 8 + 4);
            short8 sv = { f2bf(v0.x), f2bf(v0.y), f2bf(v0.z), f2bf(v0.w),
                          f2bf(v1.x), f2bf(v1.y), f2bf(v1.z), f2bf(v1.w) };
            int idx = c * 1024 + ks + i * 8;
            *(short8*)&Wlds[idx ^ ((c & 7) << 3)] = sv;
        }
    }

    const int rowb = bi * 32 + wr * 16 + kg * 4;   // first of 4 output rows
    const int arow = bi * 32 + wr * 16 + r16;      // A-fragment row (batch)
    const int col  = bj * 32 + wc * 16 + r16;      // output column
    const int wb   = wc * 16 + r16;                // W-slice row for B-fragment

    const int hrow = wr * 16 + r16;                // A row within the 32-row strip
    const char* aBase = (const char*)Hlds + hrow * 2048;
    const int hswz = (hrow & 7) << 4;              // byte XOR for Hlds reads

    const float bodec = b_ode[col];
    const float binc  = b_in[col] + b_h[col];

    f32x4 hreg = {0.f, 0.f, 0.f, 0.f};
#pragma unroll
    for (int r = 0; r < 4; ++r)   // publish h0 = 0 (device-coherent)
        __hip_atomic_store(&h0buf[(size_t)(rowb + r) * H_ + col], (unsigned short)0,
                           __ATOMIC_RELAXED, __HIP_MEMORY_SCOPE_AGENT);

    // one GLOBAL barrier: weights converted + h0 visible everywhere
    gbar(cnts + NG * 64, NB);

    unsigned* gc = cnts + bi * 64;   // this group's counter (256B-spaced lines)
    unsigned tar = GSZ;

    const unsigned short* hin = h0buf;
    unsigned short* hout = h1buf;

    // Stage this group's h strip (32 rows x 1024 cols bf16 = 64 KB) into Hlds.
    // Coalesced: lane i loads u64 at +8i (64B-line transactions). Row-major
    // LDS layout with the same XOR swizzle the MFMA read path uses.
    auto stage = [&](const unsigned short* hsrc) {
        const unsigned long long* src =
            (const unsigned long long*)(hsrc + (size_t)bi * 32 * H_);
        unsigned long long v[32];
#pragma unroll
        for (int i = 0; i < 32; ++i)
            v[i] = __hip_atomic_load(src + i * 256 + tid,
                                     __ATOMIC_RELAXED, __HIP_MEMORY_SCOPE_AGENT);
#pragma unroll
        for (int i = 0; i < 32; ++i) {
            int byte = i * 2048 + (((tid * 8) & 2047) ^ ((i & 7) << 4));
            *(unsigned long long*)((char*)Hlds + byte) = v[i];
        }
        __syncthreads();
    };

    for (int s = 0; s < S_; ++s) {
        if (s > 0) {
            const float dth = (t[s] - t[s - 1]) * 0.25f;
            for (int e = 0; e < NODE_; ++e) {
                stage(hin);
                f32x4 acc = {0.f, 0.f, 0.f, 0.f};
#pragma unroll
                for (int k0 = 0; k0 < H_; k0 += 32) {
                    short8 a = *(const short8*)(aBase + (((k0 + kg * 8) * 2) ^ hswz));
                    short8 b = *(const short8*)&Wlds[(wb * 1024 + k0 + kg * 8) ^ ((wb & 7) << 3)];
                    acc = __builtin_amdgcn_mfma_f32_16x16x32_bf16(a, b, acc, 0, 0, 0);
                }
#pragma unroll
                for (int r = 0; r < 4; ++r) {
                    hreg[r] += dth * ftanh(acc[r] + bodec);
                    __hip_atomic_store(&hout[(size_t)(rowb + r) * H_ + col],
                                       (unsigned short)f2bf(hreg[r]),
                                       __ATOMIC_RELAXED, __HIP_MEMORY_SCOPE_AGENT);
                }
                gbar(gc, tar); tar += GSZ;
                const unsigned short* tmp = hin; hin = hout; hout = (unsigned short*)tmp;
            }
        }
        // ---- update: h = tanh(x_s @ W_in^T + h @ W_h^T + b_in + b_h) ----
        {
            stage(hin);
            f32x4 acc = {0.f, 0.f, 0.f, 0.f};
            const unsigned short* whB = Whbf + (size_t)col * H_ + kg * 8;
#pragma unroll 8
            for (int k0 = 0; k0 < H_; k0 += 32) {
                short8 a = *(const short8*)(aBase + (((k0 + kg * 8) * 2) ^ hswz));
                short8 b = *(const short8*)(whB + k0);
                acc = __builtin_amdgcn_mfma_f32_16x16x32_bf16(a, b, acc, 0, 0, 0);
            }
            const float* xB = x + ((size_t)arow * S_ + s) * I_ + kg * 8;
            const unsigned short* wiB = Winbf + (size_t)col * I_ + kg * 8;
#pragma unroll
            for (int k2 = 0; k2 < I_; k2 += 32) {
                float4 a0 = *(const float4*)(xB + k2);
                float4 a1 = *(const float4*)(xB + k2 + 4);
                short8 a = { f2bf(a0.x), f2bf(a0.y), f2bf(a0.z), f2bf(a0.w),
                             f2bf(a1.x), f2bf(a1.y), f2bf(a1.z), f2bf(a1.w) };
                short8 b = *(const short8*)(wiB + k2);
                acc = __builtin_amdgcn_mfma_f32_16x16x32_bf16(a, b, acc, 0, 0, 0);
            }
            const bool last = (s == S_ - 1);
#pragma unroll
            for (int r = 0; r < 4; ++r) {
                float v = ftanh(acc[r] + binc);
                hreg[r] = v;
                if (last) {
                    out[(size_t)(rowb + r) * H_ + col] = v;
                } else {
                    __hip_atomic_store(&hout[(size_t)(rowb + r) * H_ + col],
                                       (unsigned short)f2bf(v),
                                       __ATOMIC_RELAXED, __HIP_MEMORY_SCOPE_AGENT);
                }
            }
            if (!last) {
                gbar(gc, tar); tar += GSZ;
                const unsigned short* tmp = hin; hin = hout; hout = (unsigned short*)tmp;
            }
        }
    }
}

extern "C" void kernel_launch(void* const* d_in, const int* in_sizes, int n_in,
                              void* d_out, int out_size, void* d_ws, size_t ws_size,
                              hipStream_t stream) {
    const float* x     = (const float*)d_in[0];
    const float* t     = (const float*)d_in[1];
    const float* W_in  = (const float*)d_in[2];
    const float* b_in  = (const float*)d_in[3];
    const float* W_h   = (const float*)d_in[4];
    const float* b_h   = (const float*)d_in[5];
    const float* W_ode = (const float*)d_in[6];
    const float* b_ode = (const float*)d_in[7];

    unsigned short* h0    = (unsigned short*)d_ws;
    unsigned short* h1    = h0 + (size_t)B_ * H_;
    unsigned short* Whbf  = h1 + (size_t)B_ * H_;
    unsigned short* Winbf = Whbf + (size_t)H_ * H_;
    unsigned* cnts = (unsigned*)(Winbf + (size_t)H_ * I_);   // NG*64 + 1 uints

    (void)hipMemsetAsync(cnts, 0, (NG * 64 + 1) * sizeof(unsigned), stream);

    odernn_persist<<<dim3(NB), dim3(256), 0, stream>>>(
        x, t, W_in, b_in, W_h, b_h, W_ode, b_ode,
        (float*)d_out, h0, h1, Whbf, Winbf, cnts);
}